// Round 4
// baseline (848.852 us; speedup 1.0000x reference)
//
#include <hip/hip_runtime.h>

// ---------------------------------------------------------------------------
// DIAGNOSTIC ROUND: surface the loss kernel's counters in the top-5 table.
//   probe_k: pure float4 streaming read of pred (control, duration inferred
//            from window residual).
//   loss2_k: round-3 loss kernel, TWO idempotent passes (2nd overwrites the
//            same loss[]) so its dispatch duration ~doubles and outranks the
//            ~335us poison fills -> its FETCH/BW/occupancy/VALU counters
//            become visible for the first time.
//   hist/reduce1/reduce2/scan: unchanged.
// ---------------------------------------------------------------------------

#define NB 4096
#define G  512
#define CH 16            // slab chunks in reduce1
#define SPC (G / CH)     // 32 slabs per chunk
#define SCALE 256.0f

#define E4(v)   (__expf((v).x) + __expf((v).y) + __expf((v).z) + __expf((v).w))
#define SEL4(v, t) (((t) & 2) ? (((t) & 1) ? (v).w : (v).z) \
                              : (((t) & 1) ? (v).y : (v).x))

#define LOADQ(r, v0, v1, v2, v3, tt) do {                                   \
    int _r0 = (r) + half;     if (_r0 > N - 1) _r0 = N - 1;                 \
    int _r1 = (r) + 2 + half; if (_r1 > N - 1) _r1 = N - 1;                 \
    int _r2 = (r) + 4 + half; if (_r2 > N - 1) _r2 = N - 1;                 \
    int _r3 = (r) + 6 + half; if (_r3 > N - 1) _r3 = N - 1;                 \
    v0 = p4[(size_t)_r0 * 32 + l32];                                        \
    v1 = p4[(size_t)_r1 * 32 + l32];                                        \
    v2 = p4[(size_t)_r2 * 32 + l32];                                        \
    v3 = p4[(size_t)_r3 * 32 + l32];                                        \
    int _rt = (r) + 2 * (l32 & 3) + half; if (_rt > N - 1) _rt = N - 1;     \
    tt = target[_rt];                                                       \
} while (0)

#define COMPUTEQ(r, v0, v1, v2, v3, tt) do {                                \
    float s0 = E4(v0), s1 = E4(v1), s2 = E4(v2), s3 = E4(v3);               \
    _Pragma("unroll")                                                       \
    for (int off = 1; off < 32; off <<= 1) {                                \
        s0 += __shfl_xor(s0, off);                                          \
        s1 += __shfl_xor(s1, off);                                          \
        s2 += __shfl_xor(s2, off);                                          \
        s3 += __shfl_xor(s3, off);                                          \
    }                                                                       \
    int hb = half << 5;                                                     \
    int t0 = __shfl(tt, hb + 0), t1 = __shfl(tt, hb + 1);                   \
    int t2 = __shfl(tt, hb + 2), t3 = __shfl(tt, hb + 3);                   \
    float xt0 = __shfl(SEL4(v0, t0), hb + (t0 >> 2));                       \
    float xt1 = __shfl(SEL4(v1, t1), hb + (t1 >> 2));                       \
    float xt2 = __shfl(SEL4(v2, t2), hb + (t2 >> 2));                       \
    float xt3 = __shfl(SEL4(v3, t3), hb + (t3 >> 2));                       \
    if (l32 < 4) {                                                          \
        int row  = (r) + 2 * l32 + half;                                    \
        float s  = l32 == 0 ? s0  : l32 == 1 ? s1  : l32 == 2 ? s2  : s3;   \
        float xt = l32 == 0 ? xt0 : l32 == 1 ? xt1 : l32 == 2 ? xt2 : xt3;  \
        if (row < N) loss[row] = fmaxf(__logf(s) - xt, 0.0f);               \
    }                                                                       \
} while (0)

__global__ __launch_bounds__(256) void probe_k(const float* __restrict__ pred,
                                               float* __restrict__ sink,
                                               int n4) {
    int i = blockIdx.x * 256 + threadIdx.x;
    int stride = gridDim.x * 256;
    const float4* p4 = (const float4*)pred;
    float s = 0.0f;
    for (; i < n4; i += stride) {
        float4 v = p4[i];
        s += v.x + v.y + v.z + v.w;
    }
    sink[blockIdx.x * 256 + threadIdx.x] = s;
}

__global__ __launch_bounds__(256) void loss2_k(const float* __restrict__ pred,
                                               const int* __restrict__ target,
                                               float* __restrict__ loss,
                                               int N) {
    int t    = threadIdx.x;
    int gtid = blockIdx.x * 256 + t;
    int wave = gtid >> 6;
    int lane = t & 63;
    int half = lane >> 5;              // which of the 2 rows per load instr
    int l32  = lane & 31;              // float4 index within the row
    int nw   = (gridDim.x * 256) >> 6;
    int step = nw * 8;
    const float4* p4 = (const float4*)pred;

    for (int pass = 0; pass < 2; pass++) {
        int r = wave * 8;
        if (r >= N) return;

        float4 a0, a1, a2, a3, b0, b1, b2, b3;
        int ta, tb;
        LOADQ(r, a0, a1, a2, a3, ta);
        while (r + step < N) {
            LOADQ(r + step, b0, b1, b2, b3, tb);
            COMPUTEQ(r, a0, a1, a2, a3, ta);
            r += step;
            if (r + step < N) {
                LOADQ(r + step, a0, a1, a2, a3, ta);
                COMPUTEQ(r, b0, b1, b2, b3, tb);
                r += step;
            } else {
                COMPUTEQ(r, b0, b1, b2, b3, tb);
                goto pass_done;
            }
        }
        COMPUTEQ(r, a0, a1, a2, a3, ta);
    pass_done:
        // keep the two passes distinct (no CSE across passes)
        asm volatile("" ::: "memory");
    }
}

__global__ __launch_bounds__(256) void hist_k(const float* __restrict__ loss,
                                              unsigned* __restrict__ priv_cnt,
                                              float* __restrict__ priv_sum,
                                              int N) {
    __shared__ unsigned hc[NB];
    __shared__ float    hs[NB];
    int t = threadIdx.x;
    for (int i = t; i < NB; i += 256) { hc[i] = 0u; hs[i] = 0.0f; }
    __syncthreads();

    int nv = N >> 2;
    const float4* l4 = (const float4*)loss;
    int stride = gridDim.x * 256;
    for (int i = blockIdx.x * 256 + t; i < nv; i += stride) {
        float4 v = l4[i];
        int b0 = min((int)(v.x * SCALE), NB - 1);
        atomicAdd(&hc[b0], 1u); atomicAdd(&hs[b0], v.x);
        int b1 = min((int)(v.y * SCALE), NB - 1);
        atomicAdd(&hc[b1], 1u); atomicAdd(&hs[b1], v.y);
        int b2 = min((int)(v.z * SCALE), NB - 1);
        atomicAdd(&hc[b2], 1u); atomicAdd(&hs[b2], v.z);
        int b3 = min((int)(v.w * SCALE), NB - 1);
        atomicAdd(&hc[b3], 1u); atomicAdd(&hs[b3], v.w);
    }
    for (int i = (nv << 2) + blockIdx.x * 256 + t; i < N; i += stride) {
        float v = loss[i];
        int b = min((int)(v * SCALE), NB - 1);
        atomicAdd(&hc[b], 1u); atomicAdd(&hs[b], v);
    }
    __syncthreads();
    unsigned base = blockIdx.x * NB;
    for (int i = t; i < NB; i += 256) {
        priv_cnt[base + i] = hc[i];
        priv_sum[base + i] = hs[i];
    }
}

__global__ __launch_bounds__(256) void reduce1_k(const unsigned* __restrict__ priv_cnt,
                                                 const float* __restrict__ priv_sum,
                                                 unsigned* __restrict__ pcnt,
                                                 double* __restrict__ psum) {
    int bc = blockIdx.x & 15;           // 16 bin chunks x 256 bins
    int sc = blockIdx.x >> 4;           // CH slab chunks x SPC slabs
    int bin = bc * 256 + threadIdx.x;
    int g0 = sc * SPC;
    unsigned c = 0;
    double s = 0.0;
    #pragma unroll 4
    for (int g = g0; g < g0 + SPC; g++) {
        c += priv_cnt[(size_t)g * NB + bin];
        s += (double)priv_sum[(size_t)g * NB + bin];
    }
    pcnt[(size_t)sc * NB + bin] = c;
    psum[(size_t)sc * NB + bin] = s;
}

__global__ __launch_bounds__(256) void reduce2_k(const unsigned* __restrict__ pcnt,
                                                 const double* __restrict__ psum,
                                                 unsigned* __restrict__ cnt,
                                                 double* __restrict__ dsum) {
    int bin = blockIdx.x * 256 + threadIdx.x;   // 16 blocks x 256 = 4096 bins
    unsigned c = 0;
    double s = 0.0;
    #pragma unroll
    for (int k = 0; k < CH; k++) {
        c += pcnt[(size_t)k * NB + bin];
        s += psum[(size_t)k * NB + bin];
    }
    cnt[bin] = c;
    dsum[bin] = s;
}

__global__ __launch_bounds__(256) void scan_k(const unsigned* __restrict__ cnt,
                                              const double* __restrict__ dsum,
                                              float* __restrict__ out, int K) {
    __shared__ unsigned sc[256];
    __shared__ double   ss[256];
    __shared__ int      pivot;
    __shared__ unsigned above_c;
    __shared__ double   above_s;
    int t = threadIdx.x;
    unsigned c = 0;
    double s = 0.0;
    #pragma unroll
    for (int j = 0; j < 16; j++) { c += cnt[t * 16 + j]; s += dsum[t * 16 + j]; }
    sc[t] = c;
    ss[t] = s;
    __syncthreads();
    #pragma unroll
    for (int step = 1; step < 256; step <<= 1) {
        unsigned vc = (t + step < 256) ? sc[t + step] : 0u;
        double   vs = (t + step < 256) ? ss[t + step] : 0.0;
        __syncthreads();
        sc[t] += vc;
        ss[t] += vs;
        __syncthreads();
    }
    unsigned incl = sc[t];
    unsigned abv  = (t < 255) ? sc[t + 1] : 0u;
    if (incl >= (unsigned)K && abv < (unsigned)K) {
        pivot   = t;
        above_c = abv;
        above_s = (t < 255) ? ss[t + 1] : 0.0;
    }
    __syncthreads();
    if (t == 0) {
        int pc = pivot;
        unsigned acc = above_c;
        double  accs = above_s;
        for (int b = 15; b >= 0; b--) {
            unsigned cb = cnt[pc * 16 + b];
            if (acc + cb >= (unsigned)K) {
                unsigned rIn = (unsigned)K - acc;
                double   avg = dsum[pc * 16 + b] / (double)cb;
                out[0] = (float)((accs + (double)rIn * avg) / (double)K);
                return;
            }
            acc  += cb;
            accs += dsum[pc * 16 + b];
        }
    }
}

extern "C" void kernel_launch(void* const* d_in, const int* in_sizes, int n_in,
                              void* d_out, int out_size, void* d_ws, size_t ws_size,
                              hipStream_t stream) {
    const float* pred   = (const float*)d_in[0];
    const int*   target = (const int*)d_in[1];
    int N = in_sizes[1];                    // pred is [N,128]
    int K = (int)((double)N * 0.7);         // matches python int(N*0.7)

    char* ws = (char*)d_ws;
    unsigned* priv_cnt = (unsigned*)ws;  ws += (size_t)G * NB * 4;   // 8 MB
    float*    priv_sum = (float*)ws;     ws += (size_t)G * NB * 4;   // 8 MB
    unsigned* pcnt     = (unsigned*)ws;  ws += (size_t)CH * NB * 4;  // 256 KB
    double*   psum     = (double*)ws;    ws += (size_t)CH * NB * 8;  // 512 KB
    unsigned* cnt      = (unsigned*)ws;  ws += (size_t)NB * 4;       // 16 KB
    double*   dsum     = (double*)ws;    ws += (size_t)NB * 8;       // 32 KB
    float*    loss     = (float*)ws;     ws += (size_t)4194304;      // 4 MB
    float*    sink     = (float*)ws;                                 // 2 MB

    probe_k<<<2048, 256, 0, stream>>>(pred, sink, N * 32);
    loss2_k<<<2048, 256, 0, stream>>>(pred, target, loss, N);
    hist_k<<<G, 256, 0, stream>>>(loss, priv_cnt, priv_sum, N);
    reduce1_k<<<CH * 16, 256, 0, stream>>>(priv_cnt, priv_sum, pcnt, psum);
    reduce2_k<<<NB / 256, 256, 0, stream>>>(pcnt, psum, cnt, dsum);
    scan_k<<<1, 256, 0, stream>>>(cnt, dsum, (float*)d_out, K);
}